// Round 5
// baseline (226.411 us; speedup 1.0000x reference)
//
#include <hip/hip_runtime.h>
#include <math.h>

// PCEN: x[B=64, C=128, T=4000] fp32.
// smooth[0]=x[0]; smooth[t]=(1-s)*smooth[t-1]+s*x[t], s=0.025
// out = sqrt(x/(smooth+1e-6)^0.98 + 2) - sqrt(2)
//
// Quarter-channel waves with truncated halo. Each wave independently handles
// 1000 outputs (250 float4, lane-dense) + a 256-element halo (1 float4/lane)
// with zero init: 0.975^256 = 1.5e-3 -> output error ~1e-3 << 9.6e-2
// threshold. Quarter 0 uses the exact smooth[0]=x[0] seed instead of a halo.
// 32768 independent waves (4x oversubscription, dynamic backfill), no LDS,
// no barriers, 38 shuffles/wave (vs 128 in the previous round), VGPR<=64 via
// __launch_bounds__(256,8) -> 8 waves/SIMD latency hiding.

constexpr int   TLEN  = 4000;
constexpr int   QLEN  = 1000;     // outputs per wave
constexpr int   NF4Q  = 250;      // float4s per quarter
constexpr float S_C   = 0.025f;
constexpr float A_1   = 1.0f - S_C;

constexpr float fpow(float b, int n) {
    float r = 1.0f;
    for (int i = 0; i < n; ++i) r *= b;
    return r;
}
constexpr float A_2   = fpow(A_1, 2);
constexpr float A_3   = fpow(A_1, 3);
constexpr float P4    = fpow(A_1, 4);     // a4^1
constexpr float P8    = fpow(A_1, 8);     // a4^2
constexpr float P16   = fpow(A_1, 16);    // a4^4
constexpr float P32   = fpow(A_1, 32);    // a4^8
constexpr float P64   = fpow(A_1, 64);    // a4^16
constexpr float P128  = fpow(A_1, 128);   // a4^32
constexpr float A_256 = fpow(A_1, 256);   // per-segment decay (64 lanes x 4)

constexpr float ALPHA = 0.98f;
constexpr float EPS_C = 1e-6f;
constexpr float SQRT2 = 1.41421356237309515f;

__device__ __forceinline__ float pcen_elem(float x, float sm) {
    float t  = sm + EPS_C;
    float pw = exp2f(-ALPHA * __log2f(t));   // t^-alpha  (v_log_f32 + v_exp_f32)
    float y  = fmaf(x, pw, 2.0f);            // >= 2, rsq-safe
    return y * __frsqrt_rn(y) - SQRT2;       // sqrt(y) - sqrt(2)
}

__global__ __launch_bounds__(256, 8) void pcen_kernel(const float* __restrict__ x,
                                                      float* __restrict__ out) {
    const int tid  = threadIdx.x;
    const int lane = tid & 63;
    const int qi   = tid >> 6;                 // quarter index 0..3
    const int ch   = blockIdx.x;               // one block = one channel

    const size_t  qbase = (size_t)ch * TLEN + (size_t)qi * QLEN;
    const float4* __restrict__ x4 = (const float4*)(x + qbase);
    float4*       __restrict__ o4 = (float4*)(out + qbase);

    // ---- loads: 1 halo float4 (qi>0) + 4 main float4, all lane-dense ----
    const float4* __restrict__ h4 = (const float4*)(x + qbase - 256);
    float4 h = (qi > 0) ? h4[lane] : make_float4(0.f, 0.f, 0.f, 0.f);

    float4 v[4];
    bool   act[4];
#pragma unroll
    for (int k = 0; k < 4; ++k) {
        int f4 = 64 * k + lane;
        act[k] = (f4 < NF4Q);
        v[k]   = act[k] ? x4[f4] : make_float4(0.f, 0.f, 0.f, 0.f);
    }

    // ---- per-chunk zero-init values (chunk map: sm -> 0.975^4*sm + B) ----
    float Bh = (qi > 0)
        ? fmaf(A_3, S_C * h.x, S_C * fmaf(A_2, h.y, fmaf(A_1, h.z, h.w)))
        : 0.0f;
    float B[4];
#pragma unroll
    for (int k = 0; k < 4; ++k) {
        float4 r  = v[k];
        float  b0 = (qi == 0 && k == 0 && lane == 0) ? r.x : S_C * r.x;  // exact seed
        float  w  = fmaf(A_3, b0, S_C * fmaf(A_2, r.y, fmaf(A_1, r.z, r.w)));
        B[k] = act[k] ? w : 0.0f;
    }

    // ---- constant-coefficient inclusive lane-scan, 5 interleaved segments ----
    constexpr float CD[6] = {P4, P8, P16, P32, P64, P128};
#pragma unroll
    for (int s = 0; s < 6; ++s) {
        const int   d = 1 << s;
        const float c = CD[s];
        float Hp = __shfl_up(Bh, d);
        float Bp[4];
#pragma unroll
        for (int k = 0; k < 4; ++k) Bp[k] = __shfl_up(B[k], d);
        if (lane >= d) {
            Bh = fmaf(c, Hp, Bh);
#pragma unroll
            for (int k = 0; k < 4; ++k) B[k] = fmaf(c, Bp[k], B[k]);
        }
    }

    // ---- per-lane decay 0.975^(4*lane) via bit-select products ----
    float p = 1.0f;
    if (lane & 1)  p *= P4;
    if (lane & 2)  p *= P8;
    if (lane & 4)  p *= P16;
    if (lane & 8)  p *= P32;
    if (lane & 16) p *= P64;
    if (lane & 32) p *= P128;

    // ---- chain segments (halo first), replay, epilogue, dense store ----
    float e = __shfl(Bh, 63);                  // smooth entering main (0 if qi==0)
#pragma unroll
    for (int k = 0; k < 4; ++k) {
        float Bx = __shfl_up(B[k], 1);         // lane-exclusive within segment
        if (lane == 0) Bx = 0.0f;
        float sm = fmaf(p, e, Bx);             // smooth entering this chunk

        float4 r  = v[k];
        float  b0 = (qi == 0 && k == 0 && lane == 0) ? r.x : S_C * r.x;
        float  s0 = fmaf(A_1, sm, b0);
        float  s1 = fmaf(A_1, s0, S_C * r.y);
        float  s2 = fmaf(A_1, s1, S_C * r.z);
        float  s3 = fmaf(A_1, s2, S_C * r.w);

        float4 o;
        o.x = pcen_elem(r.x, s0);
        o.y = pcen_elem(r.y, s1);
        o.z = pcen_elem(r.z, s2);
        o.w = pcen_elem(r.w, s3);

        if (act[k]) o4[64 * k + lane] = o;

        if (k < 3) e = fmaf(A_256, e, __shfl(B[k], 63));
    }
}

extern "C" void kernel_launch(void* const* d_in, const int* in_sizes, int n_in,
                              void* d_out, int out_size, void* d_ws, size_t ws_size,
                              hipStream_t stream) {
    const float* x   = (const float*)d_in[0];
    float*       out = (float*)d_out;
    const int nch    = in_sizes[0] / TLEN;   // 8192 channels
    pcen_kernel<<<nch, 256, 0, stream>>>(x, out);
}